// Round 5
// baseline (145.582 us; speedup 1.0000x reference)
//
#include <hip/hip_runtime.h>
#include <hip/hip_bf16.h>

#define NPIX 4096
#define FEAT 128
#define LAT 64
#define BS 64
#define NSTEPS 6

// flat f32 output offsets (log_m_k, log_s_k, c_f, delta, seeds)
#define OFF_LOGM  0u
#define OFF_LOGS  1835008u
#define OFF_CF    3670016u
#define OFF_DELTA 20447232u
#define OFF_SEEDS 20971520u

typedef float f32x4 __attribute__((ext_vector_type(4)));
typedef short s16x8 __attribute__((ext_vector_type(8)));
typedef short s16x4 __attribute__((ext_vector_type(4)));

__device__ __forceinline__ void amax_comb(float& bv, int& bi, float v, int i) {
    if (v > bv || (v == bv && i < bi)) { bv = v; bi = i; }
}

__device__ __forceinline__ short f2bf_rne(float r) {
    __hip_bfloat16 h = __float2bfloat16(r);
    return __builtin_bit_cast(short, h);
}

// split f32 into bf16 hi (truncated -> exact residual) + bf16 lo (RNE of residual)
__device__ __forceinline__ void split2(float v, short& hi, short& lo) {
    unsigned u = __builtin_bit_cast(unsigned, v);
    hi = (short)(u >> 16);
    float hf = __builtin_bit_cast(float, u & 0xFFFF0000u);
    lo = f2bf_rne(v - hf);
}

// 4x4 transpose among the 4 lanes of a quad (lane index b = lane&3).
// In: lane b holds row b (4 elems). Out: lane b holds column b.
__device__ __forceinline__ void transpose4(float4& v, int b) {
    float4 w;
    w.x = __shfl_xor(v.x, 1, 64); w.y = __shfl_xor(v.y, 1, 64);
    w.z = __shfl_xor(v.z, 1, 64); w.w = __shfl_xor(v.w, 1, 64);
    float4 u;
    if ((b & 1) == 0) u = make_float4(v.x, w.x, v.z, w.z);
    else              u = make_float4(w.y, v.y, w.w, v.w);
    float4 w2;
    w2.x = __shfl_xor(u.x, 2, 64); w2.y = __shfl_xor(u.y, 2, 64);
    w2.z = __shfl_xor(u.z, 2, 64); w2.w = __shfl_xor(u.w, 2, 64);
    if ((b & 2) == 0) v = make_float4(u.x, u.y, w2.x, w2.y);
    else              v = make_float4(w2.z, w2.w, u.z, u.w);
}

// ---------------------------------------------------------------------------
// K0: split gate*W into bf16 hi/lo in global scratch (16KB each, L2-resident).
// ---------------------------------------------------------------------------
__global__ void prep_w(const float* __restrict__ w, const float* __restrict__ gate_p,
                       short* __restrict__ gwh, short* __restrict__ gwl)
{
    int i = blockIdx.x * 256 + threadIdx.x;   // 8192 total
    float v = gate_p[0] * w[i];
    short h, l; split2(v, h, l);
    gwh[i] = h; gwl[i] = l;
}

// ---------------------------------------------------------------------------
// K1: 1x1 conv via split-bf16 MFMA with LDS-staged x.
// Block 256 thr (4 waves) = 256 px; grid 1024 (64 b x 16 tiles).
// Per 32-feat chunk: coalesced float4 loads -> in-reg 4x4 transpose ->
// split bf16 -> aligned b64 LDS writes [px][36]; B-frags = 2x ds_read_b64.
// A-frags: PRE ? global bf16 (prep_w) : LDS-staged W (fallback).
// ---------------------------------------------------------------------------
template<bool PRE>
__global__ __launch_bounds__(256, PRE ? 4 : 2) void conv_mfma(
    const float* __restrict__ x, const float* __restrict__ rand_pixel,
    const float* __restrict__ w, const float* __restrict__ bias,
    const float* __restrict__ gate_p, float* __restrict__ out,
    float* __restrict__ pval, int* __restrict__ pidx, int* __restrict__ cnt,
    const short* __restrict__ gwh, const short* __restrict__ gwl)
{
    __shared__ __align__(16) short Xhi[256][36];   // pitch 72B: b64-aligned, 4-way-max banks
    __shared__ __align__(16) short Xlo[256][36];
    __shared__ __align__(16) short Whi[PRE ? 1 : 64][PRE ? 1 : 136];
    __shared__ __align__(16) short Wlo[PRE ? 1 : 64][PRE ? 1 : 136];
    __shared__ float sbias[64];

    const int tid  = threadIdx.x;
    const int b    = blockIdx.x >> 4;
    const int tile = blockIdx.x & 15;
    const int p0   = tile * 256;
    const int lane = tid & 63;
    const int wv   = tid >> 6;
    const int l15  = lane & 15;
    const int lg   = lane >> 4;

    if (tile == 0 && wv == 0 && lane < 8) cnt[b * 8 + lane] = 0;

    if constexpr (!PRE) {
        const float gate = gate_p[0];
        #pragma unroll
        for (int i = 0; i < 8; ++i) {
            int q = i * 256 + tid;
            int o = q >> 5;
            int f = (q & 31) * 4;
            float4 wq = *(const float4*)(w + o * 128 + f);
            short h0, l0, h1, l1, h2, l2, h3, l3;
            split2(gate * wq.x, h0, l0);
            split2(gate * wq.y, h1, l1);
            split2(gate * wq.z, h2, l2);
            split2(gate * wq.w, h3, l3);
            *(short4*)&Whi[o][f] = make_short4(h0, h1, h2, h3);
            *(short4*)&Wlo[o][f] = make_short4(l0, l1, l2, l3);
        }
    }
    if (tid < 64) sbias[tid] = gate_p[0] * bias[tid];

    f32x4 acc[4][4];
    #pragma unroll
    for (int og = 0; og < 4; ++og)
        #pragma unroll
        for (int pg = 0; pg < 4; ++pg)
            acc[og][pg] = (f32x4){0.f, 0.f, 0.f, 0.f};

    const float* xb = x + (size_t)b * FEAT * NPIX + p0;

    for (int kc = 0; kc < 4; ++kc) {
        // ---- stage chunk kc (feats kc*32..+31, 256 px) into LDS ----
        __syncthreads();   // protect LDS from previous iteration's readers
        const float* xc = xb + (size_t)(kc * 32) * NPIX + (tid & ~3);
        #pragma unroll
        for (int i = 0; i < 8; ++i) {
            float4 v = *(const float4*)(xc + (size_t)(i * 4 + (tid & 3)) * NPIX);
            transpose4(v, tid & 3);
            // lane now holds feats kc*32+4i..+3 for px_local = tid
            short h0, l0, h1, l1, h2, l2, h3, l3;
            split2(v.x, h0, l0);
            split2(v.y, h1, l1);
            split2(v.z, h2, l2);
            split2(v.w, h3, l3);
            *(short4*)&Xhi[tid][i * 4] = make_short4(h0, h1, h2, h3);
            *(short4*)&Xlo[tid][i * 4] = make_short4(l0, l1, l2, l3);
        }
        __syncthreads();

        // ---- A fragments for this K chunk ----
        s16x8 Ah[4], Al[4];
        #pragma unroll
        for (int og = 0; og < 4; ++og) {
            if constexpr (PRE) {
                Ah[og] = *(const s16x8*)&gwh[(og * 16 + l15) * 128 + kc * 32 + lg * 8];
                Al[og] = *(const s16x8*)&gwl[(og * 16 + l15) * 128 + kc * 32 + lg * 8];
            } else {
                Ah[og] = *(const s16x8*)&Whi[og * 16 + l15][kc * 32 + lg * 8];
                Al[og] = *(const s16x8*)&Wlo[og * 16 + l15][kc * 32 + lg * 8];
            }
        }

        // ---- MFMA over 4 pixel groups ----
        #pragma unroll
        for (int pg = 0; pg < 4; ++pg) {
            int pxl = wv * 64 + pg * 16 + l15;
            const short* ph = &Xhi[pxl][lg * 8];
            const short* pl = &Xlo[pxl][lg * 8];
            s16x4 h0 = *(const s16x4*)ph, h1 = *(const s16x4*)(ph + 4);
            s16x4 q0 = *(const s16x4*)pl, q1 = *(const s16x4*)(pl + 4);
            s16x8 Bh = {h0[0], h0[1], h0[2], h0[3], h1[0], h1[1], h1[2], h1[3]};
            s16x8 Bl = {q0[0], q0[1], q0[2], q0[3], q1[0], q1[1], q1[2], q1[3]};
            #pragma unroll
            for (int og = 0; og < 4; ++og) {
                acc[og][pg] = __builtin_amdgcn_mfma_f32_16x16x32_bf16(Ah[og], Bh, acc[og][pg], 0, 0, 0);
                acc[og][pg] = __builtin_amdgcn_mfma_f32_16x16x32_bf16(Ah[og], Bl, acc[og][pg], 0, 0, 0);
                acc[og][pg] = __builtin_amdgcn_mfma_f32_16x16x32_bf16(Al[og], Bh, acc[og][pg], 0, 0, 0);
            }
        }
    }

    // epilogue: D mapping col=l15 (pixel), row=4*lg+r (out within og*16)
    float* cf = out + OFF_CF + (size_t)b * LAT * NPIX;
    #pragma unroll
    for (int og = 0; og < 4; ++og) {
        #pragma unroll
        for (int pg = 0; pg < 4; ++pg) {
            #pragma unroll
            for (int r = 0; r < 4; ++r) {
                int o = og * 16 + lg * 4 + r;
                int p = p0 + wv * 64 + pg * 16 + l15;
                float v = acc[og][pg][r] + sbias[o];
                if (o == 62) {
                    out[OFF_DELTA + ((size_t)b * 2 + 0) * NPIX + p] = v;
                    v += (float)(-1.0 + 2.0 * (double)(p >> 6) / 63.0);
                } else if (o == 63) {
                    out[OFF_DELTA + ((size_t)b * 2 + 1) * NPIX + p] = v;
                    v += (float)(-1.0 + 2.0 * (double)(p & 63) / 63.0);
                }
                cf[(size_t)o * NPIX + p] = v;
            }
        }
    }

    // wave 0 extras: zero log_s_k[0], step-0 argmax partial (probs == rand_pixel)
    if (wv == 0) {
        *(float4*)(out + OFF_LOGS + (size_t)b * NPIX + p0 + lane * 4) =
            make_float4(0.f, 0.f, 0.f, 0.f);
        float4 rv = *(const float4*)(rand_pixel + (size_t)b * NPIX + p0 + lane * 4);
        int pb = p0 + lane * 4;
        float bv = rv.x; int bi = pb;
        if (rv.y > bv) { bv = rv.y; bi = pb + 1; }
        if (rv.z > bv) { bv = rv.z; bi = pb + 2; }
        if (rv.w > bv) { bv = rv.w; bi = pb + 3; }
        #pragma unroll
        for (int off = 32; off > 0; off >>= 1) {
            float ov = __shfl_down(bv, off, 64);
            int   oi = __shfl_down(bi, off, 64);
            amax_comb(bv, bi, ov, oi);
        }
        if (lane == 0) { pval[blockIdx.x] = bv; pidx[blockIdx.x] = bi; }
    }
}

// named-register c_f: 16 x f32x4 per thread
#define REP16(OP) OP(0) OP(1) OP(2) OP(3) OP(4) OP(5) OP(6) OP(7) \
                  OP(8) OP(9) OP(10) OP(11) OP(12) OP(13) OP(14) OP(15)

// ---------------------------------------------------------------------------
// K2: fused 6-step clustering (proven round-4 structure). Block = 1024 thr =
// 1024 px, grid 256. c_f in 16 named f32x4 (coalesced transpose preload);
// d2 = |c|^2+|s|^2-2c.s; per-batch quorum-4 spin sync.
// ---------------------------------------------------------------------------
__global__ __launch_bounds__(1024) void steps_fused(
    const float* __restrict__ rand_pixel, const float* __restrict__ log_sigma_p,
    float* __restrict__ out, float* pv, int* pi, int* cnt)
{
    __shared__ float s_mv[16];
    __shared__ int   s_mi[16];
    __shared__ __align__(16) float s_seed[LAT];
    __shared__ float s_rv[16];
    __shared__ int   s_ri[16];

    const int tid  = threadIdx.x;
    const int b    = blockIdx.x >> 2;
    const int tile = blockIdx.x & 3;
    const int p    = tile * 1024 + tid;

    const float* cfb = out + OFF_CF + (size_t)b * LAT * NPIX;

#define DECLR(i) f32x4 r##i;
    REP16(DECLR)
    // coalesced preload: float4 (4px x 1ch) + 4x4 lane transpose -> own px, 4ch
#define LOADR(i) { \
        float4 v = *(const float4*)(cfb + (size_t)(4*i + (tid & 3)) * NPIX + tile * 1024 + (tid & ~3)); \
        transpose4(v, tid & 3); \
        r##i = (f32x4){v.x, v.y, v.z, v.w}; }
    REP16(LOADR)

    f32x4 aq = r0 * r0;
#define SQR(i) aq += r##i * r##i;
    SQR(1) SQR(2) SQR(3) SQR(4) SQR(5) SQR(6) SQR(7)
    SQR(8) SQR(9) SQR(10) SQR(11) SQR(12) SQR(13) SQR(14) SQR(15)
    const float cr2 = aq[0] + aq[1] + aq[2] + aq[3];

    const float rp    = rand_pixel[(size_t)b * NPIX + p];
    const float sigma = expf(log_sigma_p[0]);
    float ls = 0.f;

    #pragma unroll 1
    for (int s = 0; s < NSTEPS; ++s) {
        if (s > 0) {
            if (tid == 0) {
                while (__hip_atomic_load(&cnt[b * 8 + s], __ATOMIC_ACQUIRE,
                                         __HIP_MEMORY_SCOPE_AGENT) < 4)
                    __builtin_amdgcn_s_sleep(2);
            }
            __syncthreads();
        }
        const int nmerge = (s == 0) ? 16 : 4;
        if (tid < nmerge) {
            s_mv[tid] = __hip_atomic_load(&pv[(s * BS + b) * 16 + tid],
                                          __ATOMIC_RELAXED, __HIP_MEMORY_SCOPE_AGENT);
            s_mi[tid] = __hip_atomic_load(&pi[(s * BS + b) * 16 + tid],
                                          __ATOMIC_RELAXED, __HIP_MEMORY_SCOPE_AGENT);
        }
        __syncthreads();

        float bv = -1.0f; int bi = 0;
        for (int k = 0; k < nmerge; ++k) amax_comb(bv, bi, s_mv[k], s_mi[k]);

        if (tid < LAT) s_seed[tid] = cfb[(size_t)tid * NPIX + bi];
        __syncthreads();
        if (tile == 0 && tid < LAT)
            out[OFF_SEEDS + ((size_t)s * BS + b) * LAT + tid] = s_seed[tid];

        f32x4 dacc = (f32x4){0.f, 0.f, 0.f, 0.f};
        f32x4 sacc = (f32x4){0.f, 0.f, 0.f, 0.f};
#define DOT(i) { f32x4 sv = *(const f32x4*)&s_seed[4*i]; dacc += r##i * sv; sacc += sv * sv; }
        REP16(DOT)
        float dot = dacc[0] + dacc[1] + dacc[2] + dacc[3];
        float s2  = sacc[0] + sacc[1] + sacc[2] + sacc[3];
        float d2  = cr2 + s2 - 2.0f * dot;

        float dist  = sqrtf(fminf(fmaxf(d2, 1e-10f), 1e10f));
        float alpha = expf(-dist / sigma);
        alpha = fminf(fmaxf(alpha, 0.01f), 0.99f);
        float lm  = ls + logf(alpha);
        float lsn = ls + log1pf(-alpha);

        out[OFF_LOGM + ((size_t)s * BS + b) * NPIX + p]       = lm;
        out[OFF_LOGS + ((size_t)(s + 1) * BS + b) * NPIX + p] = lsn;
        ls = lsn;

        if (s == NSTEPS - 1) {
            out[OFF_LOGM + ((size_t)NSTEPS * BS + b) * NPIX + p] = lsn;
        } else {
            float prob = rp * expf(lsn);
            int   idx  = p;
            #pragma unroll
            for (int off = 32; off > 0; off >>= 1) {
                float ov = __shfl_down(prob, off, 64);
                int   oi = __shfl_down(idx, off, 64);
                amax_comb(prob, idx, ov, oi);
            }
            int lane = tid & 63, wid = tid >> 6;
            if (lane == 0) { s_rv[wid] = prob; s_ri[wid] = idx; }
            __syncthreads();
            if (tid == 0) {
                float fb = s_rv[0]; int fi = s_ri[0];
                #pragma unroll
                for (int k = 1; k < 16; ++k) amax_comb(fb, fi, s_rv[k], s_ri[k]);
                __hip_atomic_store(&pv[((s + 1) * BS + b) * 16 + tile], fb,
                                   __ATOMIC_RELAXED, __HIP_MEMORY_SCOPE_AGENT);
                __hip_atomic_store(&pi[((s + 1) * BS + b) * 16 + tile], fi,
                                   __ATOMIC_RELAXED, __HIP_MEMORY_SCOPE_AGENT);
                __hip_atomic_fetch_add(&cnt[b * 8 + s + 1], 1,
                                       __ATOMIC_RELEASE, __HIP_MEMORY_SCOPE_AGENT);
            }
        }
    }
}

// ---------------------------------------------------------------------------
// Fallback: per-step kernel (kernel-boundary sync) if coop launch fails.
// ---------------------------------------------------------------------------
__global__ __launch_bounds__(1024) void step_kernel(
    const float* __restrict__ rand_pixel, const float* __restrict__ log_sigma_p,
    float* __restrict__ out, float* pv, int* pi, int step)
{
    __shared__ float s_mv[16];
    __shared__ int   s_mi[16];
    __shared__ __align__(16) float s_seed[LAT];
    __shared__ float s_rv[16];
    __shared__ int   s_ri[16];

    const int tid  = threadIdx.x;
    const int b    = blockIdx.x >> 2;
    const int tile = blockIdx.x & 3;
    const int p    = tile * 1024 + tid;

    const float* cfb = out + OFF_CF + (size_t)b * LAT * NPIX;

    const int nmerge = (step == 0) ? 16 : 4;
    if (tid < nmerge) { s_mv[tid] = pv[(step * BS + b) * 16 + tid];
                        s_mi[tid] = pi[(step * BS + b) * 16 + tid]; }
    __syncthreads();
    float bv = -1.0f; int bi = 0;
    for (int k = 0; k < nmerge; ++k) amax_comb(bv, bi, s_mv[k], s_mi[k]);

    if (tid < LAT) s_seed[tid] = cfb[(size_t)tid * NPIX + bi];
    __syncthreads();
    if (tile == 0 && tid < LAT)
        out[OFF_SEEDS + ((size_t)step * BS + b) * LAT + tid] = s_seed[tid];

    float d2 = 0.f;
    #pragma unroll
    for (int c = 0; c < LAT; ++c) {
        float d = cfb[(size_t)c * NPIX + p] - s_seed[c];
        d2 = fmaf(d, d, d2);
    }
    float dist  = sqrtf(fminf(fmaxf(d2, 1e-10f), 1e10f));
    float sigma = expf(log_sigma_p[0]);
    float alpha = expf(-dist / sigma);
    alpha = fminf(fmaxf(alpha, 0.01f), 0.99f);

    float ls  = out[OFF_LOGS + ((size_t)step * BS + b) * NPIX + p];
    float lm  = ls + logf(alpha);
    float lsn = ls + log1pf(-alpha);

    out[OFF_LOGM + ((size_t)step * BS + b) * NPIX + p]       = lm;
    out[OFF_LOGS + ((size_t)(step + 1) * BS + b) * NPIX + p] = lsn;
    if (step == NSTEPS - 1)
        out[OFF_LOGM + ((size_t)NSTEPS * BS + b) * NPIX + p] = lsn;

    if (step < NSTEPS - 1) {
        float prob = rand_pixel[(size_t)b * NPIX + p] * expf(lsn);
        int   idx  = p;
        #pragma unroll
        for (int off = 32; off > 0; off >>= 1) {
            float ov = __shfl_down(prob, off, 64);
            int   oi = __shfl_down(idx, off, 64);
            amax_comb(prob, idx, ov, oi);
        }
        int lane = tid & 63, wid = tid >> 6;
        if (lane == 0) { s_rv[wid] = prob; s_ri[wid] = idx; }
        __syncthreads();
        if (tid == 0) {
            float fb = s_rv[0]; int fi = s_ri[0];
            #pragma unroll
            for (int k = 1; k < 16; ++k) amax_comb(fb, fi, s_rv[k], s_ri[k]);
            pv[((step + 1) * BS + b) * 16 + tile] = fb;
            pi[((step + 1) * BS + b) * 16 + tile] = fi;
        }
    }
}

extern "C" void kernel_launch(void* const* d_in, const int* in_sizes, int n_in,
                              void* d_out, int out_size, void* d_ws, size_t ws_size,
                              hipStream_t stream) {
    const float* x          = (const float*)d_in[0];
    const float* rand_pixel = (const float*)d_in[1];
    const float* w          = (const float*)d_in[2];
    const float* bias       = (const float*)d_in[3];
    const float* gate       = (const float*)d_in[4];
    const float* log_sigma  = (const float*)d_in[5];

    float* out = (float*)d_out;
    // ws: pv[6][64][16] f32 | pi[6][64][16] i32 | cnt[64][8] i32 | gwh 16KB | gwl 16KB
    float* pv  = (float*)d_ws;
    int*   pi  = (int*)((char*)d_ws + 24576);
    int*   cnt = (int*)((char*)d_ws + 49152);
    short* gwh = (short*)((char*)d_ws + 51200);
    short* gwl = (short*)((char*)d_ws + 67584);

    const bool pre = (ws_size >= 100 * 1024);

    if (pre) {
        prep_w<<<32, 256, 0, stream>>>(w, gate, gwh, gwl);
        conv_mfma<true><<<1024, 256, 0, stream>>>(x, rand_pixel, w, bias, gate, out,
                                                  pv, pi, cnt, gwh, gwl);
    } else {
        conv_mfma<false><<<1024, 256, 0, stream>>>(x, rand_pixel, w, bias, gate, out,
                                                   pv, pi, cnt, nullptr, nullptr);
    }

    const float* a0 = rand_pixel; const float* a1 = log_sigma; float* a2 = out;
    float* a3 = pv; int* a4 = pi; int* a5 = cnt;
    void* kp[6] = {(void*)&a0, (void*)&a1, (void*)&a2, (void*)&a3, (void*)&a4, (void*)&a5};
    hipError_t e = hipLaunchCooperativeKernel((const void*)steps_fused,
                                              dim3(256), dim3(1024), kp, 0, stream);
    if (e != hipSuccess) {
        for (int s = 0; s < NSTEPS; ++s)
            step_kernel<<<256, 1024, 0, stream>>>(rand_pixel, log_sigma, out, pv, pi, s);
    }
}

// Round 6
// 138.526 us; speedup vs baseline: 1.0509x; 1.0509x over previous
//
#include <hip/hip_runtime.h>
#include <hip/hip_bf16.h>

#define NPIX 4096
#define FEAT 128
#define LAT 64
#define BS 64
#define NSTEPS 6

// flat f32 output offsets (log_m_k, log_s_k, c_f, delta, seeds)
#define OFF_LOGM  0u
#define OFF_LOGS  1835008u
#define OFF_CF    3670016u
#define OFF_DELTA 20447232u
#define OFF_SEEDS 20971520u

typedef float f32x4 __attribute__((ext_vector_type(4)));
typedef short s16x8 __attribute__((ext_vector_type(8)));

__device__ __forceinline__ void amax_comb(float& bv, int& bi, float v, int i) {
    if (v > bv || (v == bv && i < bi)) { bv = v; bi = i; }
}

__device__ __forceinline__ short f2bf_rne(float r) {
    __hip_bfloat16 h = __float2bfloat16(r);
    return __builtin_bit_cast(short, h);
}

// split f32 into bf16 hi (truncated -> exact residual) + bf16 lo (RNE of residual)
__device__ __forceinline__ void split2(float v, short& hi, short& lo) {
    unsigned u = __builtin_bit_cast(unsigned, v);
    hi = (short)(u >> 16);
    float hf = __builtin_bit_cast(float, u & 0xFFFF0000u);
    lo = f2bf_rne(v - hf);
}

// 4x4 transpose among the 4 lanes of a quad (lane index b = lane&3).
// In: lane b holds row b (4 elems). Out: lane b holds column b.
__device__ __forceinline__ void transpose4(float4& v, int b) {
    float4 w;
    w.x = __shfl_xor(v.x, 1, 64); w.y = __shfl_xor(v.y, 1, 64);
    w.z = __shfl_xor(v.z, 1, 64); w.w = __shfl_xor(v.w, 1, 64);
    float4 u;
    if ((b & 1) == 0) u = make_float4(v.x, w.x, v.z, w.z);
    else              u = make_float4(w.y, v.y, w.w, v.w);
    float4 w2;
    w2.x = __shfl_xor(u.x, 2, 64); w2.y = __shfl_xor(u.y, 2, 64);
    w2.z = __shfl_xor(u.z, 2, 64); w2.w = __shfl_xor(u.w, 2, 64);
    if ((b & 2) == 0) v = make_float4(u.x, u.y, w2.x, w2.y);
    else              v = make_float4(w2.z, w2.w, u.z, u.w);
}

// ---------------------------------------------------------------------------
// K0: split gate*W into bf16 hi/lo in global scratch (16KB each, L2-resident).
// ---------------------------------------------------------------------------
__global__ void prep_w(const float* __restrict__ w, const float* __restrict__ gate_p,
                       short* __restrict__ gwh, short* __restrict__ gwl)
{
    int i = blockIdx.x * 256 + threadIdx.x;   // 8192 total
    float v = gate_p[0] * w[i];
    short h, l; split2(v, h, l);
    gwh[i] = h; gwl[i] = l;
}

// ---------------------------------------------------------------------------
// K1: 1x1 conv via split-bf16 MFMA, NO LDS staging. The quad-transpose of a
// float4 load (feat = kc*32+lg*8+r*4+(l15&3), px block = l15&~3) lands data
// directly in B-fragment lane order. Register double-buffer across kc.
// Block 256 thr (4 waves) = 256 px; grid 1024 (64 b x 16 tiles).
// ---------------------------------------------------------------------------
__global__ __launch_bounds__(256, 2) void conv_mfma(
    const float* __restrict__ x, const float* __restrict__ rand_pixel,
    const float* __restrict__ bias, const float* __restrict__ gate_p,
    float* __restrict__ out,
    float* __restrict__ pval, int* __restrict__ pidx, int* __restrict__ cnt,
    const short* __restrict__ gwh, const short* __restrict__ gwl)
{
    __shared__ float sbias[64];

    const int tid  = threadIdx.x;
    const int b    = blockIdx.x >> 4;
    const int tile = blockIdx.x & 15;
    const int p0   = tile * 256;
    const int lane = tid & 63;
    const int wv   = tid >> 6;
    const int l15  = lane & 15;
    const int lg   = lane >> 4;
    const int j    = l15 & 3;          // quad sub-lane

    if (tile == 0 && wv == 0 && lane < 8) cnt[b * 8 + lane] = 0;
    if (tid < 64) sbias[tid] = gate_p[0] * bias[tid];

    f32x4 acc[4][4];
    #pragma unroll
    for (int og = 0; og < 4; ++og)
        #pragma unroll
        for (int pg = 0; pg < 4; ++pg)
            acc[og][pg] = (f32x4){0.f, 0.f, 0.f, 0.f};

    // per-lane base: feat component lg*8 + j; px component wave/quad block
    const float* xq = x + (size_t)b * FEAT * NPIX
                        + (size_t)(lg * 8 + j) * NPIX
                        + p0 + wv * 64 + (l15 & ~3);

    // buf[kc&1][pg*2+r] : float4 at feat kc*32 + lg*8 + r*4 + j, px (l15&~3)+0..3
    float4 buf[2][8];

    #pragma unroll
    for (int i = 0; i < 8; ++i) {
        int pg = i >> 1, r = i & 1;
        buf[0][i] = *(const float4*)(xq + (size_t)(r * 4) * NPIX + pg * 16);
    }

    #pragma unroll
    for (int kc = 0; kc < 4; ++kc) {
        const int cur = kc & 1;
        // prefetch next chunk
        if (kc < 3) {
            #pragma unroll
            for (int i = 0; i < 8; ++i) {
                int pg = i >> 1, r = i & 1;
                buf[cur ^ 1][i] = *(const float4*)(xq + (size_t)((kc + 1) * 32 + r * 4) * NPIX + pg * 16);
            }
        }

        // A fragments (L2-hot 16KB)
        s16x8 Ah[4], Al[4];
        #pragma unroll
        for (int og = 0; og < 4; ++og) {
            Ah[og] = *(const s16x8*)&gwh[(og * 16 + l15) * 128 + kc * 32 + lg * 8];
            Al[og] = *(const s16x8*)&gwl[(og * 16 + l15) * 128 + kc * 32 + lg * 8];
        }

        #pragma unroll
        for (int pg = 0; pg < 4; ++pg) {
            float4 t0 = buf[cur][pg * 2 + 0];
            float4 t1 = buf[cur][pg * 2 + 1];
            transpose4(t0, j);   // lane now: own px (l15), feats +0..3
            transpose4(t1, j);   // feats +4..7
            s16x8 Bh, Bl;
            short h, l;
            split2(t0.x, h, l); Bh[0] = h; Bl[0] = l;
            split2(t0.y, h, l); Bh[1] = h; Bl[1] = l;
            split2(t0.z, h, l); Bh[2] = h; Bl[2] = l;
            split2(t0.w, h, l); Bh[3] = h; Bl[3] = l;
            split2(t1.x, h, l); Bh[4] = h; Bl[4] = l;
            split2(t1.y, h, l); Bh[5] = h; Bl[5] = l;
            split2(t1.z, h, l); Bh[6] = h; Bl[6] = l;
            split2(t1.w, h, l); Bh[7] = h; Bl[7] = l;
            #pragma unroll
            for (int og = 0; og < 4; ++og) {
                acc[og][pg] = __builtin_amdgcn_mfma_f32_16x16x32_bf16(Ah[og], Bh, acc[og][pg], 0, 0, 0);
                acc[og][pg] = __builtin_amdgcn_mfma_f32_16x16x32_bf16(Ah[og], Bl, acc[og][pg], 0, 0, 0);
                acc[og][pg] = __builtin_amdgcn_mfma_f32_16x16x32_bf16(Al[og], Bh, acc[og][pg], 0, 0, 0);
            }
        }
    }

    __syncthreads();   // sbias ready (cheap, once)

    // epilogue: D mapping col=l15 (pixel), row=4*lg+r (out within og*16)
    float* cf = out + OFF_CF + (size_t)b * LAT * NPIX;
    #pragma unroll
    for (int og = 0; og < 4; ++og) {
        #pragma unroll
        for (int pg = 0; pg < 4; ++pg) {
            #pragma unroll
            for (int r = 0; r < 4; ++r) {
                int o = og * 16 + lg * 4 + r;
                int p = p0 + wv * 64 + pg * 16 + l15;
                float v = acc[og][pg][r] + sbias[o];
                if (o == 62) {
                    out[OFF_DELTA + ((size_t)b * 2 + 0) * NPIX + p] = v;
                    v += (float)(-1.0 + 2.0 * (double)(p >> 6) / 63.0);
                } else if (o == 63) {
                    out[OFF_DELTA + ((size_t)b * 2 + 1) * NPIX + p] = v;
                    v += (float)(-1.0 + 2.0 * (double)(p & 63) / 63.0);
                }
                cf[(size_t)o * NPIX + p] = v;
            }
        }
    }

    // wave 0 extras: zero log_s_k[0], step-0 argmax partial (probs == rand_pixel)
    if (wv == 0) {
        *(float4*)(out + OFF_LOGS + (size_t)b * NPIX + p0 + lane * 4) =
            make_float4(0.f, 0.f, 0.f, 0.f);
        float4 rv = *(const float4*)(rand_pixel + (size_t)b * NPIX + p0 + lane * 4);
        int pb = p0 + lane * 4;
        float bv = rv.x; int bi = pb;
        if (rv.y > bv) { bv = rv.y; bi = pb + 1; }
        if (rv.z > bv) { bv = rv.z; bi = pb + 2; }
        if (rv.w > bv) { bv = rv.w; bi = pb + 3; }
        #pragma unroll
        for (int off = 32; off > 0; off >>= 1) {
            float ov = __shfl_down(bv, off, 64);
            int   oi = __shfl_down(bi, off, 64);
            amax_comb(bv, bi, ov, oi);
        }
        if (lane == 0) { pval[blockIdx.x] = bv; pidx[blockIdx.x] = bi; }
    }
}

// named-register c_f: 16 x f32x4 per thread
#define REP16(OP) OP(0) OP(1) OP(2) OP(3) OP(4) OP(5) OP(6) OP(7) \
                  OP(8) OP(9) OP(10) OP(11) OP(12) OP(13) OP(14) OP(15)

// ---------------------------------------------------------------------------
// K2: fused 6-step clustering — EXACT round-4 structure (proven ~46 us).
// Block = 1024 thr = 1024 px, grid 256 (64 b x 4 tiles). c_f in 16 named
// f32x4 (independent scalar coalesced loads); d2 = |c|^2+|s|^2-2c.s;
// per-batch quorum-4 spin sync via agent-scope atomics.
// ---------------------------------------------------------------------------
__global__ __launch_bounds__(1024) void steps_fused(
    const float* __restrict__ rand_pixel, const float* __restrict__ log_sigma_p,
    float* __restrict__ out, float* pv, int* pi, int* cnt)
{
    __shared__ float s_mv[16];
    __shared__ int   s_mi[16];
    __shared__ __align__(16) float s_seed[LAT];
    __shared__ float s_rv[16];
    __shared__ int   s_ri[16];

    const int tid  = threadIdx.x;
    const int b    = blockIdx.x >> 2;
    const int tile = blockIdx.x & 3;
    const int p    = tile * 1024 + tid;

    const float* cfb = out + OFF_CF + (size_t)b * LAT * NPIX;

#define DECLR(i) f32x4 r##i;
    REP16(DECLR)
#define LOADR(i) r##i = (f32x4){ cfb[(size_t)(4*i+0)*NPIX + p], cfb[(size_t)(4*i+1)*NPIX + p], \
                                 cfb[(size_t)(4*i+2)*NPIX + p], cfb[(size_t)(4*i+3)*NPIX + p] };
    REP16(LOADR)

    f32x4 aq = r0 * r0;
#define SQR(i) aq += r##i * r##i;
    SQR(1) SQR(2) SQR(3) SQR(4) SQR(5) SQR(6) SQR(7)
    SQR(8) SQR(9) SQR(10) SQR(11) SQR(12) SQR(13) SQR(14) SQR(15)
    const float cr2 = aq[0] + aq[1] + aq[2] + aq[3];

    const float rp    = rand_pixel[(size_t)b * NPIX + p];
    const float sigma = expf(log_sigma_p[0]);
    float ls = 0.f;

    #pragma unroll 1
    for (int s = 0; s < NSTEPS; ++s) {
        if (s > 0) {
            if (tid == 0) {
                while (__hip_atomic_load(&cnt[b * 8 + s], __ATOMIC_ACQUIRE,
                                         __HIP_MEMORY_SCOPE_AGENT) < 4)
                    __builtin_amdgcn_s_sleep(2);
            }
            __syncthreads();
        }
        const int nmerge = (s == 0) ? 16 : 4;
        if (tid < nmerge) {
            s_mv[tid] = __hip_atomic_load(&pv[(s * BS + b) * 16 + tid],
                                          __ATOMIC_RELAXED, __HIP_MEMORY_SCOPE_AGENT);
            s_mi[tid] = __hip_atomic_load(&pi[(s * BS + b) * 16 + tid],
                                          __ATOMIC_RELAXED, __HIP_MEMORY_SCOPE_AGENT);
        }
        __syncthreads();

        float bv = -1.0f; int bi = 0;
        for (int k = 0; k < nmerge; ++k) amax_comb(bv, bi, s_mv[k], s_mi[k]);

        if (tid < LAT) s_seed[tid] = cfb[(size_t)tid * NPIX + bi];
        __syncthreads();
        if (tile == 0 && tid < LAT)
            out[OFF_SEEDS + ((size_t)s * BS + b) * LAT + tid] = s_seed[tid];

        f32x4 dacc = (f32x4){0.f, 0.f, 0.f, 0.f};
        f32x4 sacc = (f32x4){0.f, 0.f, 0.f, 0.f};
#define DOT(i) { f32x4 sv = *(const f32x4*)&s_seed[4*i]; dacc += r##i * sv; sacc += sv * sv; }
        REP16(DOT)
        float dot = dacc[0] + dacc[1] + dacc[2] + dacc[3];
        float s2  = sacc[0] + sacc[1] + sacc[2] + sacc[3];
        float d2  = cr2 + s2 - 2.0f * dot;

        float dist  = sqrtf(fminf(fmaxf(d2, 1e-10f), 1e10f));
        float alpha = expf(-dist / sigma);
        alpha = fminf(fmaxf(alpha, 0.01f), 0.99f);
        float lm  = ls + logf(alpha);
        float lsn = ls + log1pf(-alpha);

        out[OFF_LOGM + ((size_t)s * BS + b) * NPIX + p]       = lm;
        out[OFF_LOGS + ((size_t)(s + 1) * BS + b) * NPIX + p] = lsn;
        ls = lsn;

        if (s == NSTEPS - 1) {
            out[OFF_LOGM + ((size_t)NSTEPS * BS + b) * NPIX + p] = lsn;
        } else {
            float prob = rp * expf(lsn);
            int   idx  = p;
            #pragma unroll
            for (int off = 32; off > 0; off >>= 1) {
                float ov = __shfl_down(prob, off, 64);
                int   oi = __shfl_down(idx, off, 64);
                amax_comb(prob, idx, ov, oi);
            }
            int lane = tid & 63, wid = tid >> 6;
            if (lane == 0) { s_rv[wid] = prob; s_ri[wid] = idx; }
            __syncthreads();
            if (tid == 0) {
                float fb = s_rv[0]; int fi = s_ri[0];
                #pragma unroll
                for (int k = 1; k < 16; ++k) amax_comb(fb, fi, s_rv[k], s_ri[k]);
                __hip_atomic_store(&pv[((s + 1) * BS + b) * 16 + tile], fb,
                                   __ATOMIC_RELAXED, __HIP_MEMORY_SCOPE_AGENT);
                __hip_atomic_store(&pi[((s + 1) * BS + b) * 16 + tile], fi,
                                   __ATOMIC_RELAXED, __HIP_MEMORY_SCOPE_AGENT);
                __hip_atomic_fetch_add(&cnt[b * 8 + s + 1], 1,
                                       __ATOMIC_RELEASE, __HIP_MEMORY_SCOPE_AGENT);
            }
        }
    }
}

// ---------------------------------------------------------------------------
// Fallback: per-step kernel (kernel-boundary sync) if coop launch fails.
// ---------------------------------------------------------------------------
__global__ __launch_bounds__(1024) void step_kernel(
    const float* __restrict__ rand_pixel, const float* __restrict__ log_sigma_p,
    float* __restrict__ out, float* pv, int* pi, int step)
{
    __shared__ float s_mv[16];
    __shared__ int   s_mi[16];
    __shared__ __align__(16) float s_seed[LAT];
    __shared__ float s_rv[16];
    __shared__ int   s_ri[16];

    const int tid  = threadIdx.x;
    const int b    = blockIdx.x >> 2;
    const int tile = blockIdx.x & 3;
    const int p    = tile * 1024 + tid;

    const float* cfb = out + OFF_CF + (size_t)b * LAT * NPIX;

    const int nmerge = (step == 0) ? 16 : 4;
    if (tid < nmerge) { s_mv[tid] = pv[(step * BS + b) * 16 + tid];
                        s_mi[tid] = pi[(step * BS + b) * 16 + tid]; }
    __syncthreads();
    float bv = -1.0f; int bi = 0;
    for (int k = 0; k < nmerge; ++k) amax_comb(bv, bi, s_mv[k], s_mi[k]);

    if (tid < LAT) s_seed[tid] = cfb[(size_t)tid * NPIX + bi];
    __syncthreads();
    if (tile == 0 && tid < LAT)
        out[OFF_SEEDS + ((size_t)step * BS + b) * LAT + tid] = s_seed[tid];

    float d2 = 0.f;
    #pragma unroll
    for (int c = 0; c < LAT; ++c) {
        float d = cfb[(size_t)c * NPIX + p] - s_seed[c];
        d2 = fmaf(d, d, d2);
    }
    float dist  = sqrtf(fminf(fmaxf(d2, 1e-10f), 1e10f));
    float sigma = expf(log_sigma_p[0]);
    float alpha = expf(-dist / sigma);
    alpha = fminf(fmaxf(alpha, 0.01f), 0.99f);

    float ls  = out[OFF_LOGS + ((size_t)step * BS + b) * NPIX + p];
    float lm  = ls + logf(alpha);
    float lsn = ls + log1pf(-alpha);

    out[OFF_LOGM + ((size_t)step * BS + b) * NPIX + p]       = lm;
    out[OFF_LOGS + ((size_t)(step + 1) * BS + b) * NPIX + p] = lsn;
    if (step == NSTEPS - 1)
        out[OFF_LOGM + ((size_t)NSTEPS * BS + b) * NPIX + p] = lsn;

    if (step < NSTEPS - 1) {
        float prob = rand_pixel[(size_t)b * NPIX + p] * expf(lsn);
        int   idx  = p;
        #pragma unroll
        for (int off = 32; off > 0; off >>= 1) {
            float ov = __shfl_down(prob, off, 64);
            int   oi = __shfl_down(idx, off, 64);
            amax_comb(prob, idx, ov, oi);
        }
        int lane = tid & 63, wid = tid >> 6;
        if (lane == 0) { s_rv[wid] = prob; s_ri[wid] = idx; }
        __syncthreads();
        if (tid == 0) {
            float fb = s_rv[0]; int fi = s_ri[0];
            #pragma unroll
            for (int k = 1; k < 16; ++k) amax_comb(fb, fi, s_rv[k], s_ri[k]);
            pv[((step + 1) * BS + b) * 16 + tile] = fb;
            pi[((step + 1) * BS + b) * 16 + tile] = fi;
        }
    }
}

extern "C" void kernel_launch(void* const* d_in, const int* in_sizes, int n_in,
                              void* d_out, int out_size, void* d_ws, size_t ws_size,
                              hipStream_t stream) {
    const float* x          = (const float*)d_in[0];
    const float* rand_pixel = (const float*)d_in[1];
    const float* w          = (const float*)d_in[2];
    const float* bias       = (const float*)d_in[3];
    const float* gate       = (const float*)d_in[4];
    const float* log_sigma  = (const float*)d_in[5];

    float* out = (float*)d_out;
    // ws: pv[6][64][16] f32 | pi[6][64][16] i32 | cnt[64][8] i32 | gwh 16KB | gwl 16KB
    float* pv  = (float*)d_ws;
    int*   pi  = (int*)((char*)d_ws + 24576);
    int*   cnt = (int*)((char*)d_ws + 49152);
    short* gwh = (short*)((char*)d_ws + 51200);
    short* gwl = (short*)((char*)d_ws + 67584);

    prep_w<<<32, 256, 0, stream>>>(w, gate, gwh, gwl);
    conv_mfma<<<1024, 256, 0, stream>>>(x, rand_pixel, bias, gate, out,
                                        pv, pi, cnt, gwh, gwl);

    const float* a0 = rand_pixel; const float* a1 = log_sigma; float* a2 = out;
    float* a3 = pv; int* a4 = pi; int* a5 = cnt;
    void* kp[6] = {(void*)&a0, (void*)&a1, (void*)&a2, (void*)&a3, (void*)&a4, (void*)&a5};
    hipError_t e = hipLaunchCooperativeKernel((const void*)steps_fused,
                                              dim3(256), dim3(1024), kp, 0, stream);
    if (e != hipSuccess) {
        for (int s = 0; s < NSTEPS; ++s)
            step_kernel<<<256, 1024, 0, stream>>>(rand_pixel, log_sigma, out, pv, pi, s);
    }
}